// Round 11
// baseline (14377.719 us; speedup 1.0000x reference)
//
#include <hip/hip_runtime.h>
#include <cstdint>
#include <cstddef>

// Autoregressive LSTM cell with softmax feedback. B=256, T=512, D=512, N=64.
// R11: XCD-LOCAL groups. R5-R10 were pinned at ~17-19us/step by the h atomic-load
// storm: agent-scope atomics are sc1-routed past L2 to the LLC fabric, and every
// group's blocks redundantly re-read the whole group h (32MB/step chip-wide at
// ~2TB/s LLC-atomic throughput). Fix: make every producer/consumer pair share an
// XCD, exchange h + flags via plain stores (dirty in the XCD's own L2) + volatile
// loads (L1 bypass; local-L2 probe sees the dirty line). No fences, no LLC on the
// recurrence path.
//  - Blocks self-organize: read HW_REG_XCC_ID, atomicAdd a slot -> group = physical
//    XCD (robust to dispatch mapping; slot>=32 -> abort, visible fail).
//  - Group = 32 rows x 32 blocks; block = 16 d-cols x 4 gates (gate = MFMA col-tile
//    -> LSTM needs no cross-lane shuffles).
//  - h/y-part gate weights (hi+lo, 144KB) in LDS; x-part weights + W_lin-hi from L2
//    during the barrier-shadow x-GEMM; xs loads NONTEMPORAL (protect LLC/L2).
//  - Numerics: R6/R10-verified fp16 hi/lo everywhere on the recurrence path.

typedef _Float16 f16x8 __attribute__((ext_vector_type(8)));
typedef float f32x4 __attribute__((ext_vector_type(4)));
typedef unsigned int u32x4 __attribute__((ext_vector_type(4)));
typedef unsigned long long u64;

#define MFMA16(a, b, c_) __builtin_amdgcn_mfma_f32_16x16x32_f16((a), (b), (c_), 0, 0, 0)
#define AGT __HIP_MEMORY_SCOPE_AGENT
#define RLX __ATOMIC_RELAXED

#define HS2_U32 131072   // per h buffer: 256 rows * 512 u32 (f16hi | f16lo<<16)
#define ABORT_OFF 16384  // flags layout: 256 slots*64 | abort | pad | xcdcnt[8]
#define XCDCNT_OFF 16448
#define FLAG_INTS 16456

static __device__ __forceinline__ unsigned short f2b(_Float16 h) {
  return __builtin_bit_cast(unsigned short, h);
}
static __device__ __forceinline__ _Float16 b2f(unsigned short s) {
  return __builtin_bit_cast(_Float16, s);
}

__device__ __forceinline__ void cvt8(const float4 a, const float4 b, f16x8& hi, f16x8& lo) {
  float v[8] = {a.x, a.y, a.z, a.w, b.x, b.y, b.z, b.w};
#pragma unroll
  for (int j = 0; j < 8; ++j) {
    _Float16 h = (_Float16)v[j];
    hi[j] = h;
    lo[j] = (_Float16)(v[j] - (float)h);
  }
}

// ---------------------------------------------------------------------------
// prep. Slot map sigma(q,j)=4q+(j&3)+16*(j>>2) on A and B frags (R2-R10 verified).
// Gates frags, slice sl = c*4 + gate (c=block d-slice 0..31, gate=i/f/g/o):
//   col = gate*512 + c*16 + (l&15); k = ki*32 + sigma.
//   ki<16 (x-part)  -> wx_hi/wx_lo planes: [(sl*16+ki)*64+l]*8
//   ki>=16 (h|y part)-> whl interleaved:   [(sl*18+(ki-16))*64+l]*16  (hi8|lo8)
// wlf_hi (y-GEMM B, hi only): [(yct*16+ki)*64+l]*8, col = yct*16+(l&15).
// hs2: u32 row-major [2][256][512] = f16hi | f16lo<<16; buffer0 = init_h.
// ---------------------------------------------------------------------------
template <bool XPRE>
__global__ void prep_kernel(const float* __restrict__ x, const float* __restrict__ init_h,
                            const float* __restrict__ W_ih, const float* __restrict__ b_ih,
                            const float* __restrict__ W_hh, const float* __restrict__ b_hh,
                            const float* __restrict__ W_lin, _Float16* __restrict__ xs,
                            _Float16* __restrict__ wx_hi, _Float16* __restrict__ wx_lo,
                            _Float16* __restrict__ whl, _Float16* __restrict__ wlf_hi,
                            unsigned int* __restrict__ hs2, float* __restrict__ bias,
                            int* __restrict__ flags) {
  const long NX = XPRE ? 256L * 512 * 16 * 4 : 0;
  const int NWF = 128 * 34 * 64;
  const int NWLF = 4 * 16 * 64;
  const int NH2 = 256 * 128;
  long tid = (long)blockIdx.x * 256 + threadIdx.x;

  if (XPRE && tid < NX) {
    int q = tid & 3, ki = (tid >> 2) & 15, t = (tid >> 6) & 511;
    int row = (int)(tid >> 15);
    const float* s = x + (((size_t)row * 512 + t) * 512 + ki * 32 + 4 * q);
    float4 a = *(const float4*)s, b = *(const float4*)(s + 16);
    f16x8 hi, lo;
    cvt8(a, b, hi, lo);
    _Float16* d = xs + ((((size_t)row * 512 + t) * 16 + ki) * 64 + q * 16);
    *(f16x8*)d = hi;
    *(f16x8*)(d + 8) = lo;
    return;
  }
  long u = tid - NX;
  if (u >= 0 && u < NWF) {
    int l = (int)(u & 63);
    int u2 = (int)(u >> 6);
    int ki = u2 % 34, sl = u2 / 34;
    int gate = sl & 3, c = sl >> 2;
    int col = gate * 512 + c * 16 + (l & 15);
    int k = ki * 32 + 4 * (l >> 4);
    float4 a, b;
    if (k < 512) {
      const float* p = W_ih + (size_t)col * 576;
      a = *(const float4*)(p + k);
      b = *(const float4*)(p + k + 16);
    } else if (k < 1024) {
      const float* p = W_hh + (size_t)col * 512;
      a = *(const float4*)(p + k - 512);
      b = *(const float4*)(p + k - 512 + 16);
    } else {
      const float* p = W_ih + (size_t)col * 576 + 512;
      a = *(const float4*)(p + k - 1024);
      b = *(const float4*)(p + k - 1024 + 16);
    }
    f16x8 hi, lo;
    cvt8(a, b, hi, lo);
    if (ki < 16) {
      size_t idx = (((size_t)sl * 16 + ki) * 64 + l) * 8;
      *(f16x8*)(wx_hi + idx) = hi;
      *(f16x8*)(wx_lo + idx) = lo;
    } else {
      size_t idx = (((size_t)sl * 18 + (ki - 16)) * 64 + l) * 16;
      *(f16x8*)(whl + idx) = hi;
      *(f16x8*)(whl + idx + 8) = lo;
    }
    return;
  }
  u -= NWF;
  if (u >= 0 && u < NWLF) {
    int l = (int)(u & 63);
    int u2 = (int)(u >> 6);
    int ki = u2 & 15, ct = u2 >> 4;
    int col = ct * 16 + (l & 15);
    int k = ki * 32 + 4 * (l >> 4);
    const float* p = W_lin + (size_t)col * 512;
    float4 a = *(const float4*)(p + k), b = *(const float4*)(p + k + 16);
    f16x8 hi, lo;
    cvt8(a, b, hi, lo);
    *(f16x8*)(wlf_hi + ((size_t)(ct * 16 + ki) * 64 + l) * 8) = hi;
    return;
  }
  u -= NWLF;
  if (u >= 0 && u < NH2) {
    int g4 = (int)(u & 127), row = (int)(u >> 7);
    const float* s = init_h + (size_t)row * 512 + g4 * 4;
    float4 a = *(const float4*)s;
    float v[4] = {a.x, a.y, a.z, a.w};
    unsigned int* d = hs2 + (size_t)row * 512 + g4 * 4;  // buffer 0
#pragma unroll
    for (int j = 0; j < 4; ++j) {
      _Float16 hh = (_Float16)v[j];
      _Float16 hl = (_Float16)(v[j] - (float)hh);
      d[j] = (unsigned int)f2b(hh) | ((unsigned int)f2b(hl) << 16);
    }
    return;
  }
  u -= NH2;
  if (u >= 0 && u < 2048) {
    bias[u] = b_ih[u] + b_hh[u];
    return;
  }
  u -= 2048;
  if (u >= 0 && u < FLAG_INTS) flags[u] = 0;
}

template <bool XPRE>
__global__ void __launch_bounds__(512, 1) recur_kernel(
    const float* __restrict__ x, const float* __restrict__ b_lin,
    const _Float16* __restrict__ xs, const _Float16* __restrict__ wx_hi,
    const _Float16* __restrict__ wx_lo, const _Float16* __restrict__ whl,
    const _Float16* __restrict__ wlf_hi, unsigned int* __restrict__ hs2,
    const float* __restrict__ bias, float* __restrict__ out, int* __restrict__ flags) {
  const int tid = threadIdx.x;
  const int l = tid & 63, w = tid >> 6;
  const int l15 = l & 15, q = l >> 4;
  const int kh = w & 1, rt = (w >> 1) & 1, ch = w >> 2;  // K-half, row-tile, gate-pair

  __shared__ _Float16 whl_lds[73728];  // 144KB: h|y-part gate B-frags (hi|lo), 4 ct
  __shared__ float scratch[2304];      // 9KB union: y-merge | ytr | gate-merge
  __shared__ int s_ab, s_g, s_c;

  // ---- self-organize into the block's PHYSICAL XCD ----
  if (tid == 0) {
    s_ab = 0;
    int xcc = __builtin_amdgcn_s_getreg(63508) & 7;  // hwreg(HW_REG_XCC_ID=20,0,32)
    int slot = __hip_atomic_fetch_add(flags + XCDCNT_OFF + xcc, 1, RLX, AGT);
    s_g = xcc;
    s_c = slot;
    if (slot >= 32) {
      __hip_atomic_store(flags + ABORT_OFF, 1, RLX, AGT);
      s_ab = 1;
    }
  }
  __syncthreads();
  if (s_ab) return;  // mis-grouped -> peers time out -> visible failure (no hang)
  const int g = s_g, c = s_c;
  const int ct0 = ch * 2, ct1 = ch * 2 + 1;

  {  // stage this block's h|y-part gate weights into LDS (9216 float4 units)
    const _Float16* src = whl + (size_t)c * 73728;
#pragma unroll
    for (int i = 0; i < 18; ++i) {
      int uu = tid + i * 512;
      *(float4*)(whl_lds + (size_t)uu * 8) = *(const float4*)(src + (size_t)uu * 8);
    }
  }
  __syncthreads();

  float bg[4];
#pragma unroll
  for (int gi = 0; gi < 4; ++gi) bg[gi] = bias[gi * 512 + c * 16 + l15];
  const float blv0 = b_lin[l15], blv1 = b_lin[16 + l15];
  const float blv2 = b_lin[32 + l15], blv3 = b_lin[48 + l15];

  const int rowA = g * 32 + rt * 16 + l15;  // A-frag source row (global)
  const _Float16* xsA = xs + (size_t)rowA * 524288 + q * 16;
  const float* xfA = x + (size_t)rowA * 262144 + 4 * q;
  const unsigned int* hldA = hs2 + (size_t)rowA * 512 + 4 * q;

  int* abortf = flags + ABORT_OFF;

  auto ARRIVE = [&](int v) {
    __syncthreads();  // drains this block's h stores (vmcnt) before the flag
    if (tid == 0) *(volatile int*)(flags + (size_t)(g * 32 + c) * 64) = v;
  };
  auto WAIT = [&](int v) -> bool {
    if (tid < 32) {
      int a = 0;
      volatile int* f = (volatile int*)(flags + ((size_t)g * 32 + tid) * 64);
      int it = 0;
      while (*f < v) {
        __builtin_amdgcn_s_sleep(1);
        if (++it > 300000) {
          a = 1;
          break;
        }
        if ((it & 255) == 0 && __hip_atomic_load(abortf, RLX, AGT) != 0) {
          a = 1;
          break;
        }
      }
      a = __any(a) ? 1 : 0;
      if (tid == 0) {
        if (a) __hip_atomic_store(abortf, 1, RLX, AGT);
        s_ab = a;
      }
    }
    __syncthreads();
    return s_ab != 0;
  };

  // gates k-chunk, 3-pass hi/lo, B from LDS (h-part kidx 0..15, y-part 16..17)
  auto GKH = [&](const f16x8& ah, const f16x8& al, int kidx, f32x4& A0, f32x4& A1) {
    const _Float16* p0 = whl_lds + (((size_t)ct0 * 18 + kidx) * 64 + l) * 16;
    const _Float16* p1 = whl_lds + (((size_t)ct1 * 18 + kidx) * 64 + l) * 16;
    f16x8 b0h = *(const f16x8*)p0, b0l = *(const f16x8*)(p0 + 8);
    f16x8 b1h = *(const f16x8*)p1, b1l = *(const f16x8*)(p1 + 8);
    A0 = MFMA16(ah, b0h, A0);
    A1 = MFMA16(ah, b1h, A1);
    A0 = MFMA16(al, b0h, A0);
    A1 = MFMA16(al, b1h, A1);
    A0 = MFMA16(ah, b0l, A0);
    A1 = MFMA16(ah, b1l, A1);
  };
  // x-part k-chunk, B from GLOBAL planes (L2-resident; runs in barrier shadow)
  auto GKX = [&](const f16x8& ah, const f16x8& al, int ki, f32x4& A0, f32x4& A1) {
    size_t i0 = (((size_t)(c * 4 + ct0) * 16 + ki) * 64 + l) * 8;
    size_t i1 = (((size_t)(c * 4 + ct1) * 16 + ki) * 64 + l) * 8;
    f16x8 b0h = *(const f16x8*)(wx_hi + i0), b0l = *(const f16x8*)(wx_lo + i0);
    f16x8 b1h = *(const f16x8*)(wx_hi + i1), b1l = *(const f16x8*)(wx_lo + i1);
    A0 = MFMA16(ah, b0h, A0);
    A1 = MFMA16(ah, b1h, A1);
    A0 = MFMA16(al, b0h, A0);
    A1 = MFMA16(al, b1h, A1);
    A0 = MFMA16(ah, b0l, A0);
    A1 = MFMA16(ah, b1l, A1);
  };
  auto XGEMM = [&](int t, f32x4& A0, f32x4& A1) {
    if (XPRE) {
      const _Float16* xA = xsA + (size_t)t * 1024;
#pragma unroll
      for (int i = 0; i < 8; ++i) {
        int kx = kh * 8 + i;
        union {
          u32x4 u;
          f16x8 v;
        } ua, ub;
        ua.u = __builtin_nontemporal_load((const u32x4*)(xA + kx * 64));
        ub.u = __builtin_nontemporal_load((const u32x4*)(xA + kx * 64 + 8));
        GKX(ua.v, ub.v, kx, A0, A1);
      }
    } else {
      const float* xp = xfA + (size_t)t * 512;
#pragma unroll 2
      for (int i = 0; i < 8; ++i) {
        int kx = kh * 8 + i;
        float4 av = *(const float4*)(xp + kx * 32);
        float4 bv = *(const float4*)(xp + kx * 32 + 16);
        f16x8 ah, al;
        cvt8(av, bv, ah, al);
        GKX(ah, al, kx, A0, A1);
      }
    }
  };

  const f32x4 Z = {0.f, 0.f, 0.f, 0.f};
  float cst[4] = {0.f, 0.f, 0.f, 0.f};  // cell state: 4 rows per lane, all 512 steps
  f32x4 aC0 = Z, aC1 = Z;
  XGEMM(0, aC0, aC1);  // x-part of step 0

#pragma unroll 1
  for (int s = 0; s < 512; ++s) {
    if (s > 0) {
      if (WAIT(s)) return;  // h_{s-1} published by the group's 32 blocks (via L2)
    }

    // ---- h frag loads: volatile u64 (L1-bypass; local-L2 probe sees dirty h) ----
    f16x8 hh[8], hl[8];
    const unsigned int* hp0 = hldA + (size_t)(s & 1) * HS2_U32;
#pragma unroll
    for (int i = 0; i < 8; ++i) {
      const unsigned int* hp = hp0 + (kh * 8 + i) * 32;
      u64 u0 = *(const volatile u64*)hp;
      u64 u1 = *(const volatile u64*)(hp + 2);
      u64 u2 = *(const volatile u64*)(hp + 16);
      u64 u3 = *(const volatile u64*)(hp + 18);
      unsigned int wd[8] = {(unsigned int)u0, (unsigned int)(u0 >> 32),
                            (unsigned int)u1, (unsigned int)(u1 >> 32),
                            (unsigned int)u2, (unsigned int)(u2 >> 32),
                            (unsigned int)u3, (unsigned int)(u3 >> 32)};
#pragma unroll
      for (int j = 0; j < 8; ++j) {
        hh[i][j] = b2f((unsigned short)(wd[j] & 0xffffu));
        hl[i][j] = b2f((unsigned short)(wd[j] >> 16));
      }
    }

    // ---- y-GEMM partials (ch==0 waves; B = W_lin-hi from L2, 2-pass) ----
    f32x4 y0 = Z, y1 = Z, y2 = Z, y3 = Z;
    if (s > 0 && ch == 0) {
#pragma unroll
      for (int i = 0; i < 8; ++i) {
        int ki = kh * 8 + i;
        f16x8 b0 = *(const f16x8*)(wlf_hi + (((size_t)(0 * 16 + ki)) * 64 + l) * 8);
        f16x8 b1 = *(const f16x8*)(wlf_hi + (((size_t)(1 * 16 + ki)) * 64 + l) * 8);
        f16x8 b2 = *(const f16x8*)(wlf_hi + (((size_t)(2 * 16 + ki)) * 64 + l) * 8);
        f16x8 b3 = *(const f16x8*)(wlf_hi + (((size_t)(3 * 16 + ki)) * 64 + l) * 8);
        y0 = MFMA16(hh[i], b0, y0);
        y1 = MFMA16(hh[i], b1, y1);
        y2 = MFMA16(hh[i], b2, y2);
        y3 = MFMA16(hh[i], b3, y3);
        y0 = MFMA16(hl[i], b0, y0);
        y1 = MFMA16(hl[i], b1, y1);
        y2 = MFMA16(hl[i], b2, y2);
        y3 = MFMA16(hl[i], b3, y3);
      }
    }
    // ---- h-GEMM (B from LDS) ----
#pragma unroll
    for (int i = 0; i < 8; ++i) GKH(hh[i], hl[i], kh * 8 + i, aC0, aC1);

    if (s > 0) {
      if (ch == 0 && kh == 1) {  // y K-half dump
#pragma unroll
        for (int r = 0; r < 4; ++r) {
          scratch[((rt * 4 + 0) * 4 + r) * 64 + l] = y0[r];
          scratch[((rt * 4 + 1) * 4 + r) * 64 + l] = y1[r];
          scratch[((rt * 4 + 2) * 4 + r) * 64 + l] = y2[r];
          scratch[((rt * 4 + 3) * 4 + r) * 64 + l] = y3[r];
        }
      }
      __syncthreads();  // S1
      if (ch == 0 && kh == 0) {
        float la[4][4];
#pragma unroll
        for (int r = 0; r < 4; ++r) {
          la[0][r] = y0[r] + scratch[((rt * 4 + 0) * 4 + r) * 64 + l] + blv0;
          la[1][r] = y1[r] + scratch[((rt * 4 + 1) * 4 + r) * 64 + l] + blv1;
          la[2][r] = y2[r] + scratch[((rt * 4 + 2) * 4 + r) * 64 + l] + blv2;
          la[3][r] = y3[r] + scratch[((rt * 4 + 3) * 4 + r) * 64 + l] + blv3;
        }
#pragma unroll
        for (int r = 0; r < 4; ++r) {  // softmax over 64 cols (16 lanes x 4 ct)
          float mx = fmaxf(fmaxf(la[0][r], la[1][r]), fmaxf(la[2][r], la[3][r]));
          mx = fmaxf(mx, __shfl_xor(mx, 1));
          mx = fmaxf(mx, __shfl_xor(mx, 2));
          mx = fmaxf(mx, __shfl_xor(mx, 4));
          mx = fmaxf(mx, __shfl_xor(mx, 8));
          float e0 = __expf(la[0][r] - mx), e1 = __expf(la[1][r] - mx);
          float e2 = __expf(la[2][r] - mx), e3 = __expf(la[3][r] - mx);
          float sm = e0 + e1 + e2 + e3;
          sm += __shfl_xor(sm, 1);
          sm += __shfl_xor(sm, 2);
          sm += __shfl_xor(sm, 4);
          sm += __shfl_xor(sm, 8);
          float inv = 1.f / sm;
          la[0][r] = e0 * inv;
          la[1][r] = e1 * inv;
          la[2][r] = e2 * inv;
          la[3][r] = e3 * inv;
        }
        // distributed out-write: this block owns y-cols 2c, 2c+1
#pragma unroll
        for (int j2 = 0; j2 < 2; ++j2) {
          int n = 2 * c + j2;
          if (l15 == (n & 15)) {
#pragma unroll
            for (int r = 0; r < 4; ++r)
              out[((size_t)(g * 32 + rt * 16 + 4 * q + r) * 512 + (s - 1)) * 64 + n] =
                  la[n >> 4][r];
          }
        }
        // ytr (hi|lo planes) for the y-feedback A-frags
        _Float16* yt = (_Float16*)scratch;
#pragma unroll
        for (int r = 0; r < 4; ++r) {
          int row = rt * 16 + 4 * q + r;
#pragma unroll
          for (int ct = 0; ct < 4; ++ct) {
            _Float16 vh = (_Float16)la[ct][r];
            _Float16 vl = (_Float16)(la[ct][r] - (float)vh);
            yt[row * 136 + ct * 16 + l15] = vh;
            yt[row * 136 + 72 + ct * 16 + l15] = vl;
          }
        }
      }
      __syncthreads();  // S2: ytr ready
      {
        const _Float16* yt = (const _Float16*)scratch + (rt * 16 + l15) * 136 + kh * 32 + 4 * q;
        union {
          u64 d[2];
          f16x8 v;
        } th, tl;
        th.d[0] = *(const u64*)yt;
        th.d[1] = *(const u64*)(yt + 16);
        tl.d[0] = *(const u64*)(yt + 72);
        tl.d[1] = *(const u64*)(yt + 88);
        GKH(th.v, tl.v, 16 + kh, aC0, aC1);  // y-feedback k-chunk (hi/lo, LDS B)
      }
      __syncthreads();  // S3: ytr reads done; scratch free for gate merge
    }

    // ---- 4-way gate merge (kh x ch) ----
    if (kh == 1) {  // dump partials: [rt][gate][r][l]
#pragma unroll
      for (int r = 0; r < 4; ++r) {
        scratch[((rt * 4 + ct0) * 4 + r) * 64 + l] = aC0[r];
        scratch[((rt * 4 + ct1) * 4 + r) * 64 + l] = aC1[r];
      }
    }
    __syncthreads();  // S4
    if (kh == 0) {
#pragma unroll
      for (int r = 0; r < 4; ++r) {
        aC0[r] += scratch[((rt * 4 + ct0) * 4 + r) * 64 + l];
        aC1[r] += scratch[((rt * 4 + ct1) * 4 + r) * 64 + l];
      }
      if (ch == 1) {  // publish summed g,o for the LSTM waves
#pragma unroll
        for (int r = 0; r < 4; ++r) {
          scratch[((rt * 4 + 2) * 4 + r) * 64 + l] = aC0[r];
          scratch[((rt * 4 + 3) * 4 + r) * 64 + l] = aC1[r];
        }
      }
    }
    __syncthreads();  // S5
    if (kh == 0 && ch == 0) {
      // ---- elementwise LSTM: lane owns rows rt*16+4q+r (r=0..3), d = 16c+l15 ----
      const unsigned int wbuf = (unsigned int)(((s + 1) & 1) * HS2_U32);
      const int dglob = c * 16 + l15;
#pragma unroll
      for (int r = 0; r < 4; ++r) {
        float zi = aC0[r] + bg[0];
        float zf = aC1[r] + bg[1];
        float zg = scratch[((rt * 4 + 2) * 4 + r) * 64 + l] + bg[2];
        float zo = scratch[((rt * 4 + 3) * 4 + r) * 64 + l] + bg[3];
        float iv = 1.f / (1.f + __expf(-zi));
        float fv = 1.f / (1.f + __expf(-zf));
        float eg = __expf(2.f * zg);
        float gv = 1.f - 2.f / (eg + 1.f);
        float ov = 1.f / (1.f + __expf(-zo));
        float cn = fv * cst[r] + iv * gv;
        cst[r] = cn;
        float ec = __expf(2.f * cn);
        float th2 = 1.f - 2.f / (ec + 1.f);
        float hv = ov * th2;
        _Float16 hhv = (_Float16)hv;
        _Float16 hlv = (_Float16)(hv - (float)hhv);
        unsigned int pk = (unsigned int)f2b(hhv) | ((unsigned int)f2b(hlv) << 16);
        int grow = g * 32 + rt * 16 + 4 * q + r;
        hs2[wbuf + (size_t)grow * 512 + dglob] = pk;  // PLAIN store -> local L2
      }
    }
    ARRIVE(s + 1);  // drain + publish h_s (group-local flag via L2)
    if (s < 511) {  // next-step x-GEMM runs in the barrier's propagation shadow
      f32x4 aN0 = Z, aN1 = Z;
      XGEMM(s + 1, aN0, aN1);
      aC0 = aN0;
      aC1 = aN1;
    }
  }

  // ---- epilogue: y_511 from h_511 (buffer 0) ----
  if (WAIT(512)) return;
  {
    f16x8 hh[8], hl[8];
#pragma unroll
    for (int i = 0; i < 8; ++i) {
      const unsigned int* hp = hldA + (kh * 8 + i) * 32;  // buffer (512&1)==0
      u64 u0 = *(const volatile u64*)hp;
      u64 u1 = *(const volatile u64*)(hp + 2);
      u64 u2 = *(const volatile u64*)(hp + 16);
      u64 u3 = *(const volatile u64*)(hp + 18);
      unsigned int wd[8] = {(unsigned int)u0, (unsigned int)(u0 >> 32),
                            (unsigned int)u1, (unsigned int)(u1 >> 32),
                            (unsigned int)u2, (unsigned int)(u2 >> 32),
                            (unsigned int)u3, (unsigned int)(u3 >> 32)};
#pragma unroll
      for (int j = 0; j < 8; ++j) {
        hh[i][j] = b2f((unsigned short)(wd[j] & 0xffffu));
        hl[i][j] = b2f((unsigned short)(wd[j] >> 16));
      }
    }
    f32x4 y0 = Z, y1 = Z, y2 = Z, y3 = Z;
    if (ch == 0) {
#pragma unroll
      for (int i = 0; i < 8; ++i) {
        int ki = kh * 8 + i;
        f16x8 b0 = *(const f16x8*)(wlf_hi + (((size_t)(0 * 16 + ki)) * 64 + l) * 8);
        f16x8 b1 = *(const f16x8*)(wlf_hi + (((size_t)(1 * 16 + ki)) * 64 + l) * 8);
        f16x8 b2 = *(const f16x8*)(wlf_hi + (((size_t)(2 * 16 + ki)) * 64 + l) * 8);
        f16x8 b3 = *(const f16x8*)(wlf_hi + (((size_t)(3 * 16 + ki)) * 64 + l) * 8);
        y0 = MFMA16(hh[i], b0, y0);
        y1 = MFMA16(hh[i], b1, y1);
        y2 = MFMA16(hh[i], b2, y2);
        y3 = MFMA16(hh[i], b3, y3);
        y0 = MFMA16(hl[i], b0, y0);
        y1 = MFMA16(hl[i], b1, y1);
        y2 = MFMA16(hl[i], b2, y2);
        y3 = MFMA16(hl[i], b3, y3);
      }
      if (kh == 1) {
#pragma unroll
        for (int r = 0; r < 4; ++r) {
          scratch[((rt * 4 + 0) * 4 + r) * 64 + l] = y0[r];
          scratch[((rt * 4 + 1) * 4 + r) * 64 + l] = y1[r];
          scratch[((rt * 4 + 2) * 4 + r) * 64 + l] = y2[r];
          scratch[((rt * 4 + 3) * 4 + r) * 64 + l] = y3[r];
        }
      }
    }
    __syncthreads();
    if (ch == 0 && kh == 0) {
      float la[4][4];
#pragma unroll
      for (int r = 0; r < 4; ++r) {
        la[0][r] = y0[r] + scratch[((rt * 4 + 0) * 4 + r) * 64 + l] + blv0;
        la[1][r] = y1[r] + scratch[((rt * 4 + 1) * 4 + r) * 64 + l] + blv1;
        la[2][r] = y2[r] + scratch[((rt * 4 + 2) * 4 + r) * 64 + l] + blv2;
        la[3][r] = y3[r] + scratch[((rt * 4 + 3) * 4 + r) * 64 + l] + blv3;
      }
#pragma unroll
      for (int r = 0; r < 4; ++r) {
        float mx = fmaxf(fmaxf(la[0][r], la[1][r]), fmaxf(la[2][r], la[3][r]));
        mx = fmaxf(mx, __shfl_xor(mx, 1));
        mx = fmaxf(mx, __shfl_xor(mx, 2));
        mx = fmaxf(mx, __shfl_xor(mx, 4));
        mx = fmaxf(mx, __shfl_xor(mx, 8));
        float e0 = __expf(la[0][r] - mx), e1 = __expf(la[1][r] - mx);
        float e2 = __expf(la[2][r] - mx), e3 = __expf(la[3][r] - mx);
        float sm = e0 + e1 + e2 + e3;
        sm += __shfl_xor(sm, 1);
        sm += __shfl_xor(sm, 2);
        sm += __shfl_xor(sm, 4);
        sm += __shfl_xor(sm, 8);
        float inv = 1.f / sm;
        la[0][r] = e0 * inv;
        la[1][r] = e1 * inv;
        la[2][r] = e2 * inv;
        la[3][r] = e3 * inv;
      }
#pragma unroll
      for (int j2 = 0; j2 < 2; ++j2) {
        int n = 2 * c + j2;
        if (l15 == (n & 15)) {
#pragma unroll
          for (int r = 0; r < 4; ++r)
            out[((size_t)(g * 32 + rt * 16 + 4 * q + r) * 512 + 511) * 64 + n] = la[n >> 4][r];
        }
      }
    }
  }
}

extern "C" void kernel_launch(void* const* d_in, const int* in_sizes, int n_in, void* d_out,
                              int out_size, void* d_ws, size_t ws_size, hipStream_t stream) {
  const float* x = (const float*)d_in[0];
  const float* init_h = (const float*)d_in[1];
  const float* W_ih = (const float*)d_in[2];
  const float* b_ih = (const float*)d_in[3];
  const float* W_hh = (const float*)d_in[4];
  const float* b_hh = (const float*)d_in[5];
  const float* W_lin = (const float*)d_in[6];
  const float* b_lin = (const float*)d_in[7];
  float* out = (float*)d_out;
  (void)in_sizes;
  (void)n_in;
  (void)out_size;

  char* ws = (char*)d_ws;
  size_t off = 0;
  auto take = [&](size_t bytes) -> char* {
    char* r = ws + off;
    off = (off + bytes + 255) & ~(size_t)255;
    return r;
  };
  const size_t WX_E = (size_t)128 * 16 * 64 * 8;    // x-part gate frags, per plane
  const size_t WHL_E = (size_t)128 * 18 * 64 * 16;  // h|y-part gate frags (hi|lo)
  const size_t WLF_E = (size_t)4 * 16 * 64 * 8;     // W_lin hi frags
  const size_t XS_E = (size_t)256 * 512 * 16 * 64;  // pre-split x frags

  _Float16* wx_hi = (_Float16*)take(WX_E * 2);
  _Float16* wx_lo = (_Float16*)take(WX_E * 2);
  _Float16* whl = (_Float16*)take(WHL_E * 2);
  _Float16* wlf_hi = (_Float16*)take(WLF_E * 2);
  unsigned int* hs2 = (unsigned int*)take((size_t)2 * HS2_U32 * 4);
  float* bias = (float*)take(2048 * 4);
  int* flags = (int*)take((size_t)FLAG_INTS * 4);
  if (ws_size < off) return;  // cannot run -> visible failure
  _Float16* xs = (_Float16*)(ws + off);
  const bool xpre = (ws_size >= off + XS_E * 2);

  if (xpre) {
    const long total = 8388608L + 278528 + 4096 + 32768 + 2048 + FLAG_INTS;
    prep_kernel<true><<<(int)((total + 255) / 256), 256, 0, stream>>>(
        x, init_h, W_ih, b_ih, W_hh, b_hh, W_lin, xs, wx_hi, wx_lo, whl, wlf_hi, hs2, bias,
        flags);
    recur_kernel<true><<<256, 512, 0, stream>>>(x, b_lin, xs, wx_hi, wx_lo, whl, wlf_hi, hs2,
                                                bias, out, flags);
  } else {
    const long total = 278528L + 4096 + 32768 + 2048 + FLAG_INTS;
    prep_kernel<false><<<(int)((total + 255) / 256), 256, 0, stream>>>(
        x, init_h, W_ih, b_ih, W_hh, b_hh, W_lin, xs, wx_hi, wx_lo, whl, wlf_hi, hs2, bias,
        flags);
    recur_kernel<false><<<256, 512, 0, stream>>>(x, b_lin, xs, wx_hi, wx_lo, whl, wlf_hi, hs2,
                                                 bias, out, flags);
  }
}

// Round 12
// 10883.903 us; speedup vs baseline: 1.3210x; 1.3210x over previous
//
#include <hip/hip_runtime.h>
#include <cstdint>
#include <cstddef>

// Autoregressive LSTM cell with softmax feedback. B=256, T=512, D=512, N=64.
// R12: x-projection HOISTED out of the recurrence (cuDNN-LSTM trick).
// R11 diagnosis: 24.4 MB/step of x-weight re-streaming (4MB/XCD > L2) = the whole
// 28us step. Fix: prep_gx precomputes gx[b,t,4D] = x@Wx^T (fp32, 1.07GB ws) as a
// dense GEMM; the recurrence keeps only h/y GEMMs with ALL their weights in LDS
// (hi/lo SPLIT planes -> 16B-stride conflict-free reads, fixes R11's 1.7e8 confl).
// Per-XCD L2 in the loop: h (128KB) + W_lin-hi (64KB) + read-once gx stream. No
// gate weights touch L2/HBM per step.
// Kept verbatim from R11 (verified): XCD-local groups via HW_REG_XCC_ID, plain-
// store/volatile-load h+flag exchange through local L2, timeout barrier, hi/lo
// numerics on every recurrence operand, distributed out-write, LSTM gate layout.
// Fallback (ws too small for gx): R11's per-step x-GEMM path (correct, slow).

typedef _Float16 f16x8 __attribute__((ext_vector_type(8)));
typedef float f32x4 __attribute__((ext_vector_type(4)));
typedef unsigned long long u64;

#define MFMA16(a, b, c_) __builtin_amdgcn_mfma_f32_16x16x32_f16((a), (b), (c_), 0, 0, 0)
#define AGT __HIP_MEMORY_SCOPE_AGENT
#define RLX __ATOMIC_RELAXED

#define HS2_U32 131072   // per h buffer: 256 rows * 512 u32 (f16hi | f16lo<<16)
#define ABORT_OFF 16384  // flags: 256 slots*64 | abort | pad | xcdcnt[8]
#define XCDCNT_OFF 16448
#define FLAG_INTS 16456

static __device__ __forceinline__ unsigned short f2b(_Float16 h) {
  return __builtin_bit_cast(unsigned short, h);
}
static __device__ __forceinline__ _Float16 b2f(unsigned short s) {
  return __builtin_bit_cast(_Float16, s);
}

__device__ __forceinline__ void cvt8(const float4 a, const float4 b, f16x8& hi, f16x8& lo) {
  float v[8] = {a.x, a.y, a.z, a.w, b.x, b.y, b.z, b.w};
#pragma unroll
  for (int j = 0; j < 8; ++j) {
    _Float16 h = (_Float16)v[j];
    hi[j] = h;
    lo[j] = (_Float16)(v[j] - (float)h);
  }
}

// ---------------------------------------------------------------------------
// prep. Slot map sigma(q,j)=4q+(j&3)+16*(j>>2) on A and B frags (R2-R11 verified).
// Gate frags, slice sl = c*4 + gate: col = gate*512 + c*16 + (l&15).
//   ki<16 (x-part) -> wx_hi/wx_lo planes: [(sl*16+ki)*64+l]*8   (feeds prep_gx)
//   ki>=16 (h|y)   -> whl_hi/whl_lo planes: [(sl*18+(ki-16))*64+l]*8  (-> LDS)
// wlf_hi (y-GEMM B, hi only): [(yct*16+ki)*64+l]*8, col = yct*16+(l&15).
// hs2: u32 row-major [2][256][512] = f16hi | f16lo<<16; buffer0 = init_h.
// ---------------------------------------------------------------------------
__global__ void prep_kernel(const float* __restrict__ x, const float* __restrict__ init_h,
                            const float* __restrict__ W_ih, const float* __restrict__ b_ih,
                            const float* __restrict__ W_hh, const float* __restrict__ b_hh,
                            const float* __restrict__ W_lin, _Float16* __restrict__ wx_hi,
                            _Float16* __restrict__ wx_lo, _Float16* __restrict__ whl_hi,
                            _Float16* __restrict__ whl_lo, _Float16* __restrict__ wlf_hi,
                            unsigned int* __restrict__ hs2, float* __restrict__ bias,
                            int* __restrict__ flags) {
  const int NWF = 128 * 34 * 64;
  const int NWLF = 4 * 16 * 64;
  const int NH2 = 256 * 128;
  long u = (long)blockIdx.x * 256 + threadIdx.x;

  if (u < NWF) {
    int l = (int)(u & 63);
    int u2 = (int)(u >> 6);
    int ki = u2 % 34, sl = u2 / 34;
    int gate = sl & 3, c = sl >> 2;
    int col = gate * 512 + c * 16 + (l & 15);
    int k = ki * 32 + 4 * (l >> 4);
    float4 a, b;
    if (k < 512) {
      const float* p = W_ih + (size_t)col * 576;
      a = *(const float4*)(p + k);
      b = *(const float4*)(p + k + 16);
    } else if (k < 1024) {
      const float* p = W_hh + (size_t)col * 512;
      a = *(const float4*)(p + k - 512);
      b = *(const float4*)(p + k - 512 + 16);
    } else {
      const float* p = W_ih + (size_t)col * 576 + 512;
      a = *(const float4*)(p + k - 1024);
      b = *(const float4*)(p + k - 1024 + 16);
    }
    f16x8 hi, lo;
    cvt8(a, b, hi, lo);
    if (ki < 16) {
      size_t idx = (((size_t)sl * 16 + ki) * 64 + l) * 8;
      *(f16x8*)(wx_hi + idx) = hi;
      *(f16x8*)(wx_lo + idx) = lo;
    } else {
      size_t idx = (((size_t)sl * 18 + (ki - 16)) * 64 + l) * 8;
      *(f16x8*)(whl_hi + idx) = hi;
      *(f16x8*)(whl_lo + idx) = lo;
    }
    return;
  }
  u -= NWF;
  if (u >= 0 && u < NWLF) {
    int l = (int)(u & 63);
    int u2 = (int)(u >> 6);
    int ki = u2 & 15, ct = u2 >> 4;
    int col = ct * 16 + (l & 15);
    int k = ki * 32 + 4 * (l >> 4);
    const float* p = W_lin + (size_t)col * 512;
    float4 a = *(const float4*)(p + k), b = *(const float4*)(p + k + 16);
    f16x8 hi, lo;
    cvt8(a, b, hi, lo);
    *(f16x8*)(wlf_hi + ((size_t)(ct * 16 + ki) * 64 + l) * 8) = hi;
    return;
  }
  u -= NWLF;
  if (u >= 0 && u < NH2) {
    int g4 = (int)(u & 127), row = (int)(u >> 7);
    const float* s = init_h + (size_t)row * 512 + g4 * 4;
    float4 a = *(const float4*)s;
    float v[4] = {a.x, a.y, a.z, a.w};
    unsigned int* d = hs2 + (size_t)row * 512 + g4 * 4;  // buffer 0
#pragma unroll
    for (int j = 0; j < 4; ++j) {
      _Float16 hh = (_Float16)v[j];
      _Float16 hl = (_Float16)(v[j] - (float)hh);
      d[j] = (unsigned int)f2b(hh) | ((unsigned int)f2b(hl) << 16);
    }
    return;
  }
  u -= NH2;
  if (u >= 0 && u < 2048) {
    bias[u] = b_ih[u] + b_hh[u];
    return;
  }
  u -= 2048;
  if (u >= 0 && u < FLAG_INTS) flags[u] = 0;
}

// ---------------------------------------------------------------------------
// prep_gx: gx[t*256+row][2048] = x[row,t,:] @ Wx^T (fp32, 3-pass hi/lo).
// grid (8192, 8): blockIdx.x = t*16 + row16; wave w -> c = blockIdx.y*4 + w.
// Reuses R11-verified pieces: cvt8 A-build, wx frag layout, C-map (col=l15,row=4q+r).
// ---------------------------------------------------------------------------
__global__ void __launch_bounds__(256) prep_gx_kernel(const float* __restrict__ x,
                                                      const _Float16* __restrict__ wx_hi,
                                                      const _Float16* __restrict__ wx_lo,
                                                      float* __restrict__ gx) {
  const int t = blockIdx.x >> 4, row16 = blockIdx.x & 15;
  const int w = threadIdx.x >> 6, l = threadIdx.x & 63;
  const int l15 = l & 15, q = l >> 4;
  const int c = blockIdx.y * 4 + w;

  const float* xp = x + (((size_t)(row16 * 16 + l15) * 512 + t) * 512) + 4 * q;
  const f32x4 Z = {0.f, 0.f, 0.f, 0.f};
  f32x4 acc[4] = {Z, Z, Z, Z};
#pragma unroll 2
  for (int ki = 0; ki < 16; ++ki) {
    float4 av = *(const float4*)(xp + ki * 32);
    float4 bv = *(const float4*)(xp + ki * 32 + 16);
    f16x8 ah, al;
    cvt8(av, bv, ah, al);
#pragma unroll
    for (int gate = 0; gate < 4; ++gate) {
      size_t idx = (((size_t)(c * 4 + gate) * 16 + ki) * 64 + l) * 8;
      f16x8 bh = *(const f16x8*)(wx_hi + idx);
      f16x8 bl = *(const f16x8*)(wx_lo + idx);
      acc[gate] = MFMA16(ah, bh, acc[gate]);
      acc[gate] = MFMA16(al, bh, acc[gate]);
      acc[gate] = MFMA16(ah, bl, acc[gate]);
    }
  }
#pragma unroll
  for (int gate = 0; gate < 4; ++gate)
#pragma unroll
    for (int r = 0; r < 4; ++r)
      gx[((size_t)t * 256 + row16 * 16 + 4 * q + r) * 2048 + gate * 512 + c * 16 + l15] =
          acc[gate][r];
}

template <bool GXP>
__global__ void __launch_bounds__(512, 1) recur_kernel(
    const float* __restrict__ x, const float* __restrict__ b_lin,
    const _Float16* __restrict__ wx_hi, const _Float16* __restrict__ wx_lo,
    const _Float16* __restrict__ whl_hi_g, const _Float16* __restrict__ whl_lo_g,
    const _Float16* __restrict__ wlf_hi, const float* __restrict__ gx,
    unsigned int* __restrict__ hs2, const float* __restrict__ bias, float* __restrict__ out,
    int* __restrict__ flags) {
  const int tid = threadIdx.x;
  const int l = tid & 63, w = tid >> 6;
  const int l15 = l & 15, q = l >> 4;
  const int kh = w & 1, rt = (w >> 1) & 1, ch = w >> 2;  // K-half, row-tile, gate-pair

  __shared__ _Float16 whl_h[36864];  // 72KB h|y-part gate B-frag hi (4 gates x 18 ki)
  __shared__ _Float16 whl_l[36864];  // 72KB lo plane (separate -> 16B-stride reads)
  __shared__ float scratch[2304];    // 9KB union: y-merge | ytr | gate-merge
  __shared__ int s_ab, s_g, s_c;

  // ---- self-organize into the block's PHYSICAL XCD (R11-verified) ----
  if (tid == 0) {
    s_ab = 0;
    int xcc = __builtin_amdgcn_s_getreg(63508) & 7;  // HW_REG_XCC_ID
    int slot = __hip_atomic_fetch_add(flags + XCDCNT_OFF + xcc, 1, RLX, AGT);
    s_g = xcc;
    s_c = slot;
    if (slot >= 32) {
      __hip_atomic_store(flags + ABORT_OFF, 1, RLX, AGT);
      s_ab = 1;
    }
  }
  __syncthreads();
  if (s_ab) return;  // peers time out -> visible failure (no hang)
  const int g = s_g, c = s_c;
  const int ct0 = ch * 2, ct1 = ch * 2 + 1;

  {  // stage this block's h|y-part gate weights: 4608 float4 units per plane
    const _Float16* sh = whl_hi_g + (size_t)c * 36864;
    const _Float16* slo = whl_lo_g + (size_t)c * 36864;
#pragma unroll
    for (int i = 0; i < 9; ++i) {
      int uu = tid + i * 512;
      *(float4*)(whl_h + (size_t)uu * 8) = *(const float4*)(sh + (size_t)uu * 8);
      *(float4*)(whl_l + (size_t)uu * 8) = *(const float4*)(slo + (size_t)uu * 8);
    }
  }
  __syncthreads();

  float bg[4];
#pragma unroll
  for (int gi = 0; gi < 4; ++gi) bg[gi] = bias[gi * 512 + c * 16 + l15];
  const float blv0 = b_lin[l15], blv1 = b_lin[16 + l15];
  const float blv2 = b_lin[32 + l15], blv3 = b_lin[48 + l15];

  const int rowA = g * 32 + rt * 16 + l15;  // A-frag source row (global)
  const float* xfA = x + (size_t)rowA * 262144 + 4 * q;
  const unsigned int* hldA = hs2 + (size_t)rowA * 512 + 4 * q;

  int* abortf = flags + ABORT_OFF;

  auto ARRIVE = [&](int v) {
    __syncthreads();  // drains this block's h stores (vmcnt) before the flag
    if (tid == 0) *(volatile int*)(flags + (size_t)(g * 32 + c) * 64) = v;
  };
  auto WAIT = [&](int v) -> bool {
    if (tid < 32) {
      int a = 0;
      volatile int* f = (volatile int*)(flags + ((size_t)g * 32 + tid) * 64);
      int it = 0;
      while (*f < v) {
        __builtin_amdgcn_s_sleep(1);
        if (++it > 300000) {
          a = 1;
          break;
        }
        if ((it & 255) == 0 && __hip_atomic_load(abortf, RLX, AGT) != 0) {
          a = 1;
          break;
        }
      }
      a = __any(a) ? 1 : 0;
      if (tid == 0) {
        if (a) __hip_atomic_store(abortf, 1, RLX, AGT);
        s_ab = a;
      }
    }
    __syncthreads();
    return s_ab != 0;
  };

  // h|y k-chunk, 3-pass hi/lo, B from split LDS planes (kidx 0..15 h, 16..17 y)
  auto GKH = [&](const f16x8& ah, const f16x8& al, int kidx, f32x4& A0, f32x4& A1) {
    const _Float16* p0h = whl_h + (((size_t)ct0 * 18 + kidx) * 64 + l) * 8;
    const _Float16* p1h = whl_h + (((size_t)ct1 * 18 + kidx) * 64 + l) * 8;
    const _Float16* p0l = whl_l + (((size_t)ct0 * 18 + kidx) * 64 + l) * 8;
    const _Float16* p1l = whl_l + (((size_t)ct1 * 18 + kidx) * 64 + l) * 8;
    f16x8 b0h = *(const f16x8*)p0h, b1h = *(const f16x8*)p1h;
    f16x8 b0l = *(const f16x8*)p0l, b1l = *(const f16x8*)p1l;
    A0 = MFMA16(ah, b0h, A0);
    A1 = MFMA16(ah, b1h, A1);
    A0 = MFMA16(al, b0h, A0);
    A1 = MFMA16(al, b1h, A1);
    A0 = MFMA16(ah, b0l, A0);
    A1 = MFMA16(ah, b1l, A1);
  };
  // fallback x k-chunk (streams wx from global; only used when !GXP)
  auto GKX = [&](const f16x8& ah, const f16x8& al, int ki, f32x4& A0, f32x4& A1) {
    size_t i0 = (((size_t)(c * 4 + ct0) * 16 + ki) * 64 + l) * 8;
    size_t i1 = (((size_t)(c * 4 + ct1) * 16 + ki) * 64 + l) * 8;
    f16x8 b0h = *(const f16x8*)(wx_hi + i0), b0l = *(const f16x8*)(wx_lo + i0);
    f16x8 b1h = *(const f16x8*)(wx_hi + i1), b1l = *(const f16x8*)(wx_lo + i1);
    A0 = MFMA16(ah, b0h, A0);
    A1 = MFMA16(ah, b1h, A1);
    A0 = MFMA16(al, b0h, A0);
    A1 = MFMA16(al, b1h, A1);
    A0 = MFMA16(ah, b0l, A0);
    A1 = MFMA16(ah, b1l, A1);
  };
  auto XGEMM = [&](int t, f32x4& A0, f32x4& A1) {
    const float* xp = xfA + (size_t)t * 512;
#pragma unroll 2
    for (int i = 0; i < 8; ++i) {
      int kx = kh * 8 + i;
      float4 av = *(const float4*)(xp + kx * 32);
      float4 bv = *(const float4*)(xp + kx * 32 + 16);
      f16x8 ah, al;
      cvt8(av, bv, ah, al);
      GKX(ah, al, kx, A0, A1);
    }
  };

  const f32x4 Z = {0.f, 0.f, 0.f, 0.f};
  float cst[4] = {0.f, 0.f, 0.f, 0.f};  // cell state: 4 rows/lane, all 512 steps
  f32x4 aC0 = Z, aC1 = Z;
  if (!GXP) XGEMM(0, aC0, aC1);  // fallback: x-part of step 0

#pragma unroll 1
  for (int s = 0; s < 512; ++s) {
    // ---- gx prefetch for this step (independent of the barrier) ----
    float gxv[4][4];
    if (GXP && kh == 0 && ch == 0) {
#pragma unroll
      for (int r = 0; r < 4; ++r) {
        const float* gp = gx + ((size_t)s * 256 + g * 32 + rt * 16 + 4 * q + r) * 2048 +
                          c * 16 + l15;
#pragma unroll
        for (int gate = 0; gate < 4; ++gate) gxv[gate][r] = gp[gate * 512];
      }
    }

    if (s > 0) {
      if (WAIT(s)) return;  // h_{s-1} published by the group's 32 blocks (via L2)
    }

    // ---- h frag loads: volatile u64 (L1-bypass; local-L2 dirty lines) ----
    f16x8 hh[8], hl[8];
    const unsigned int* hp0 = hldA + (size_t)(s & 1) * HS2_U32;
#pragma unroll
    for (int i = 0; i < 8; ++i) {
      const unsigned int* hp = hp0 + (kh * 8 + i) * 32;
      u64 u0 = *(const volatile u64*)hp;
      u64 u1 = *(const volatile u64*)(hp + 2);
      u64 u2 = *(const volatile u64*)(hp + 16);
      u64 u3 = *(const volatile u64*)(hp + 18);
      unsigned int wd[8] = {(unsigned int)u0, (unsigned int)(u0 >> 32),
                            (unsigned int)u1, (unsigned int)(u1 >> 32),
                            (unsigned int)u2, (unsigned int)(u2 >> 32),
                            (unsigned int)u3, (unsigned int)(u3 >> 32)};
#pragma unroll
      for (int j = 0; j < 8; ++j) {
        hh[i][j] = b2f((unsigned short)(wd[j] & 0xffffu));
        hl[i][j] = b2f((unsigned short)(wd[j] >> 16));
      }
    }

    // ---- y-GEMM partials (ch==0 waves; B = W_lin-hi from L2, 2-pass) ----
    f32x4 y0 = Z, y1 = Z, y2 = Z, y3 = Z;
    if (s > 0 && ch == 0) {
#pragma unroll
      for (int i = 0; i < 8; ++i) {
        int ki = kh * 8 + i;
        f16x8 b0 = *(const f16x8*)(wlf_hi + (((size_t)(0 * 16 + ki)) * 64 + l) * 8);
        f16x8 b1 = *(const f16x8*)(wlf_hi + (((size_t)(1 * 16 + ki)) * 64 + l) * 8);
        f16x8 b2 = *(const f16x8*)(wlf_hi + (((size_t)(2 * 16 + ki)) * 64 + l) * 8);
        f16x8 b3 = *(const f16x8*)(wlf_hi + (((size_t)(3 * 16 + ki)) * 64 + l) * 8);
        y0 = MFMA16(hh[i], b0, y0);
        y1 = MFMA16(hh[i], b1, y1);
        y2 = MFMA16(hh[i], b2, y2);
        y3 = MFMA16(hh[i], b3, y3);
        y0 = MFMA16(hl[i], b0, y0);
        y1 = MFMA16(hl[i], b1, y1);
        y2 = MFMA16(hl[i], b2, y2);
        y3 = MFMA16(hl[i], b3, y3);
      }
    }
    // ---- h-GEMM (B from LDS) ----
    if (GXP) {
      aC0 = Z;
      aC1 = Z;
    }
#pragma unroll
    for (int i = 0; i < 8; ++i) GKH(hh[i], hl[i], kh * 8 + i, aC0, aC1);

    if (s > 0) {
      if (ch == 0 && kh == 1) {  // y K-half dump
#pragma unroll
        for (int r = 0; r < 4; ++r) {
          scratch[((rt * 4 + 0) * 4 + r) * 64 + l] = y0[r];
          scratch[((rt * 4 + 1) * 4 + r) * 64 + l] = y1[r];
          scratch[((rt * 4 + 2) * 4 + r) * 64 + l] = y2[r];
          scratch[((rt * 4 + 3) * 4 + r) * 64 + l] = y3[r];
        }
      }
      __syncthreads();  // S1
      if (ch == 0 && kh == 0) {
        float la[4][4];
#pragma unroll
        for (int r = 0; r < 4; ++r) {
          la[0][r] = y0[r] + scratch[((rt * 4 + 0) * 4 + r) * 64 + l] + blv0;
          la[1][r] = y1[r] + scratch[((rt * 4 + 1) * 4 + r) * 64 + l] + blv1;
          la[2][r] = y2[r] + scratch[((rt * 4 + 2) * 4 + r) * 64 + l] + blv2;
          la[3][r] = y3[r] + scratch[((rt * 4 + 3) * 4 + r) * 64 + l] + blv3;
        }
#pragma unroll
        for (int r = 0; r < 4; ++r) {  // softmax over 64 cols (16 lanes x 4 ct)
          float mx = fmaxf(fmaxf(la[0][r], la[1][r]), fmaxf(la[2][r], la[3][r]));
          mx = fmaxf(mx, __shfl_xor(mx, 1));
          mx = fmaxf(mx, __shfl_xor(mx, 2));
          mx = fmaxf(mx, __shfl_xor(mx, 4));
          mx = fmaxf(mx, __shfl_xor(mx, 8));
          float e0 = __expf(la[0][r] - mx), e1 = __expf(la[1][r] - mx);
          float e2 = __expf(la[2][r] - mx), e3 = __expf(la[3][r] - mx);
          float sm = e0 + e1 + e2 + e3;
          sm += __shfl_xor(sm, 1);
          sm += __shfl_xor(sm, 2);
          sm += __shfl_xor(sm, 4);
          sm += __shfl_xor(sm, 8);
          float inv = 1.f / sm;
          la[0][r] = e0 * inv;
          la[1][r] = e1 * inv;
          la[2][r] = e2 * inv;
          la[3][r] = e3 * inv;
        }
        // distributed out-write: this block owns y-cols 2c, 2c+1
#pragma unroll
        for (int j2 = 0; j2 < 2; ++j2) {
          int n = 2 * c + j2;
          if (l15 == (n & 15)) {
#pragma unroll
            for (int r = 0; r < 4; ++r)
              out[((size_t)(g * 32 + rt * 16 + 4 * q + r) * 512 + (s - 1)) * 64 + n] =
                  la[n >> 4][r];
          }
        }
        // ytr (hi|lo planes) for the y-feedback A-frags
        _Float16* yt = (_Float16*)scratch;
#pragma unroll
        for (int r = 0; r < 4; ++r) {
          int row = rt * 16 + 4 * q + r;
#pragma unroll
          for (int ct = 0; ct < 4; ++ct) {
            _Float16 vh = (_Float16)la[ct][r];
            _Float16 vl = (_Float16)(la[ct][r] - (float)vh);
            yt[row * 136 + ct * 16 + l15] = vh;
            yt[row * 136 + 72 + ct * 16 + l15] = vl;
          }
        }
      }
      __syncthreads();  // S2: ytr ready
      {
        const _Float16* yt = (const _Float16*)scratch + (rt * 16 + l15) * 136 + kh * 32 + 4 * q;
        union {
          u64 d[2];
          f16x8 v;
        } th, tl;
        th.d[0] = *(const u64*)yt;
        th.d[1] = *(const u64*)(yt + 16);
        tl.d[0] = *(const u64*)(yt + 72);
        tl.d[1] = *(const u64*)(yt + 88);
        GKH(th.v, tl.v, 16 + kh, aC0, aC1);  // y-feedback k-chunk (hi/lo, LDS B)
      }
      __syncthreads();  // S3: ytr reads done; scratch free for gate merge
    }

    // ---- 4-way gate merge (kh x ch) ----
    if (kh == 1) {
#pragma unroll
      for (int r = 0; r < 4; ++r) {
        scratch[((rt * 4 + ct0) * 4 + r) * 64 + l] = aC0[r];
        scratch[((rt * 4 + ct1) * 4 + r) * 64 + l] = aC1[r];
      }
    }
    __syncthreads();  // S4
    if (kh == 0) {
#pragma unroll
      for (int r = 0; r < 4; ++r) {
        aC0[r] += scratch[((rt * 4 + ct0) * 4 + r) * 64 + l];
        aC1[r] += scratch[((rt * 4 + ct1) * 4 + r) * 64 + l];
      }
      if (ch == 1) {  // publish summed g,o for the LSTM waves
#pragma unroll
        for (int r = 0; r < 4; ++r) {
          scratch[((rt * 4 + 2) * 4 + r) * 64 + l] = aC0[r];
          scratch[((rt * 4 + 3) * 4 + r) * 64 + l] = aC1[r];
        }
      }
    }
    __syncthreads();  // S5
    if (kh == 0 && ch == 0) {
      // ---- elementwise LSTM: lane owns rows rt*16+4q+r, d = 16c+l15 ----
      const unsigned int wbuf = (unsigned int)(((s + 1) & 1) * HS2_U32);
      const int dglob = c * 16 + l15;
#pragma unroll
      for (int r = 0; r < 4; ++r) {
        float gx0 = GXP ? gxv[0][r] : 0.f, gx1 = GXP ? gxv[1][r] : 0.f;
        float gx2 = GXP ? gxv[2][r] : 0.f, gx3 = GXP ? gxv[3][r] : 0.f;
        float zi = aC0[r] + bg[0] + gx0;
        float zf = aC1[r] + bg[1] + gx1;
        float zg = scratch[((rt * 4 + 2) * 4 + r) * 64 + l] + bg[2] + gx2;
        float zo = scratch[((rt * 4 + 3) * 4 + r) * 64 + l] + bg[3] + gx3;
        float iv = 1.f / (1.f + __expf(-zi));
        float fv = 1.f / (1.f + __expf(-zf));
        float eg = __expf(2.f * zg);
        float gv = 1.f - 2.f / (eg + 1.f);
        float ov = 1.f / (1.f + __expf(-zo));
        float cn = fv * cst[r] + iv * gv;
        cst[r] = cn;
        float ec = __expf(2.f * cn);
        float th2 = 1.f - 2.f / (ec + 1.f);
        float hv = ov * th2;
        _Float16 hhv = (_Float16)hv;
        _Float16 hlv = (_Float16)(hv - (float)hhv);
        unsigned int pk = (unsigned int)f2b(hhv) | ((unsigned int)f2b(hlv) << 16);
        int grow = g * 32 + rt * 16 + 4 * q + r;
        hs2[wbuf + (size_t)grow * 512 + dglob] = pk;  // PLAIN store -> local L2
      }
    }
    ARRIVE(s + 1);  // drain + publish h_s (group-local flag via L2)
    if (!GXP && s < 511) {  // fallback: next-step x-GEMM in the barrier shadow
      f32x4 aN0 = Z, aN1 = Z;
      XGEMM(s + 1, aN0, aN1);
      aC0 = aN0;
      aC1 = aN1;
    }
  }

  // ---- epilogue: y_511 from h_511 (buffer 0) ----
  if (WAIT(512)) return;
  {
    f16x8 hh[8], hl[8];
#pragma unroll
    for (int i = 0; i < 8; ++i) {
      const unsigned int* hp = hldA + (kh * 8 + i) * 32;  // buffer (512&1)==0
      u64 u0 = *(const volatile u64*)hp;
      u64 u1 = *(const volatile u64*)(hp + 2);
      u64 u2 = *(const volatile u64*)(hp + 16);
      u64 u3 = *(const volatile u64*)(hp + 18);
      unsigned int wd[8] = {(unsigned int)u0, (unsigned int)(u0 >> 32),
                            (unsigned int)u1, (unsigned int)(u1 >> 32),
                            (unsigned int)u2, (unsigned int)(u2 >> 32),
                            (unsigned int)u3, (unsigned int)(u3 >> 32)};
#pragma unroll
      for (int j = 0; j < 8; ++j) {
        hh[i][j] = b2f((unsigned short)(wd[j] & 0xffffu));
        hl[i][j] = b2f((unsigned short)(wd[j] >> 16));
      }
    }
    f32x4 y0 = Z, y1 = Z, y2 = Z, y3 = Z;
    if (ch == 0) {
#pragma unroll
      for (int i = 0; i < 8; ++i) {
        int ki = kh * 8 + i;
        f16x8 b0 = *(const f16x8*)(wlf_hi + (((size_t)(0 * 16 + ki)) * 64 + l) * 8);
        f16x8 b1 = *(const f16x8*)(wlf_hi + (((size_t)(1 * 16 + ki)) * 64 + l) * 8);
        f16x8 b2 = *(const f16x8*)(wlf_hi + (((size_t)(2 * 16 + ki)) * 64 + l) * 8);
        f16x8 b3 = *(const f16x8*)(wlf_hi + (((size_t)(3 * 16 + ki)) * 64 + l) * 8);
        y0 = MFMA16(hh[i], b0, y0);
        y1 = MFMA16(hh[i], b1, y1);
        y2 = MFMA16(hh[i], b2, y2);
        y3 = MFMA16(hh[i], b3, y3);
        y0 = MFMA16(hl[i], b0, y0);
        y1 = MFMA16(hl[i], b1, y1);
        y2 = MFMA16(hl[i], b2, y2);
        y3 = MFMA16(hl[i], b3, y3);
      }
      if (kh == 1) {
#pragma unroll
        for (int r = 0; r < 4; ++r) {
          scratch[((rt * 4 + 0) * 4 + r) * 64 + l] = y0[r];
          scratch[((rt * 4 + 1) * 4 + r) * 64 + l] = y1[r];
          scratch[((rt * 4 + 2) * 4 + r) * 64 + l] = y2[r];
          scratch[((rt * 4 + 3) * 4 + r) * 64 + l] = y3[r];
        }
      }
    }
    __syncthreads();
    if (ch == 0 && kh == 0) {
      float la[4][4];
#pragma unroll
      for (int r = 0; r < 4; ++r) {
        la[0][r] = y0[r] + scratch[((rt * 4 + 0) * 4 + r) * 64 + l] + blv0;
        la[1][r] = y1[r] + scratch[((rt * 4 + 1) * 4 + r) * 64 + l] + blv1;
        la[2][r] = y2[r] + scratch[((rt * 4 + 2) * 4 + r) * 64 + l] + blv2;
        la[3][r] = y3[r] + scratch[((rt * 4 + 3) * 4 + r) * 64 + l] + blv3;
      }
#pragma unroll
      for (int r = 0; r < 4; ++r) {
        float mx = fmaxf(fmaxf(la[0][r], la[1][r]), fmaxf(la[2][r], la[3][r]));
        mx = fmaxf(mx, __shfl_xor(mx, 1));
        mx = fmaxf(mx, __shfl_xor(mx, 2));
        mx = fmaxf(mx, __shfl_xor(mx, 4));
        mx = fmaxf(mx, __shfl_xor(mx, 8));
        float e0 = __expf(la[0][r] - mx), e1 = __expf(la[1][r] - mx);
        float e2 = __expf(la[2][r] - mx), e3 = __expf(la[3][r] - mx);
        float sm = e0 + e1 + e2 + e3;
        sm += __shfl_xor(sm, 1);
        sm += __shfl_xor(sm, 2);
        sm += __shfl_xor(sm, 4);
        sm += __shfl_xor(sm, 8);
        float inv = 1.f / sm;
        la[0][r] = e0 * inv;
        la[1][r] = e1 * inv;
        la[2][r] = e2 * inv;
        la[3][r] = e3 * inv;
      }
#pragma unroll
      for (int j2 = 0; j2 < 2; ++j2) {
        int n = 2 * c + j2;
        if (l15 == (n & 15)) {
#pragma unroll
          for (int r = 0; r < 4; ++r)
            out[((size_t)(g * 32 + rt * 16 + 4 * q + r) * 512 + 511) * 64 + n] = la[n >> 4][r];
        }
      }
    }
  }
}

extern "C" void kernel_launch(void* const* d_in, const int* in_sizes, int n_in, void* d_out,
                              int out_size, void* d_ws, size_t ws_size, hipStream_t stream) {
  const float* x = (const float*)d_in[0];
  const float* init_h = (const float*)d_in[1];
  const float* W_ih = (const float*)d_in[2];
  const float* b_ih = (const float*)d_in[3];
  const float* W_hh = (const float*)d_in[4];
  const float* b_hh = (const float*)d_in[5];
  const float* W_lin = (const float*)d_in[6];
  const float* b_lin = (const float*)d_in[7];
  float* out = (float*)d_out;
  (void)in_sizes;
  (void)n_in;
  (void)out_size;

  char* ws = (char*)d_ws;
  size_t off = 0;
  auto take = [&](size_t bytes) -> char* {
    char* r = ws + off;
    off = (off + bytes + 255) & ~(size_t)255;
    return r;
  };
  const size_t WX_E = (size_t)128 * 16 * 64 * 8;    // x-part gate frags, per plane
  const size_t WHL_E = (size_t)128 * 18 * 64 * 8;   // h|y-part gate frags, per plane
  const size_t WLF_E = (size_t)4 * 16 * 64 * 8;     // W_lin hi frags
  const size_t GX_E = (size_t)512 * 256 * 2048;     // precomputed x-gates (fp32)

  _Float16* wx_hi = (_Float16*)take(WX_E * 2);
  _Float16* wx_lo = (_Float16*)take(WX_E * 2);
  _Float16* whl_hi = (_Float16*)take(WHL_E * 2);
  _Float16* whl_lo = (_Float16*)take(WHL_E * 2);
  _Float16* wlf_hi = (_Float16*)take(WLF_E * 2);
  unsigned int* hs2 = (unsigned int*)take((size_t)2 * HS2_U32 * 4);
  float* bias = (float*)take(2048 * 4);
  int* flags = (int*)take((size_t)FLAG_INTS * 4);
  if (ws_size < off) return;  // cannot run -> visible failure
  float* gxp = (float*)(ws + off);
  const bool gxok = (ws_size >= off + GX_E * 4);

  const long total = 278528L + 4096 + 32768 + 2048 + FLAG_INTS;
  prep_kernel<<<(int)((total + 255) / 256), 256, 0, stream>>>(
      x, init_h, W_ih, b_ih, W_hh, b_hh, W_lin, wx_hi, wx_lo, whl_hi, whl_lo, wlf_hi, hs2, bias,
      flags);
  if (gxok) {
    prep_gx_kernel<<<dim3(8192, 8), 256, 0, stream>>>(x, wx_hi, wx_lo, gxp);
    recur_kernel<true><<<256, 512, 0, stream>>>(x, b_lin, wx_hi, wx_lo, whl_hi, whl_lo, wlf_hi,
                                                gxp, hs2, bias, out, flags);
  } else {
    recur_kernel<false><<<256, 512, 0, stream>>>(x, b_lin, wx_hi, wx_lo, whl_hi, whl_lo, wlf_hi,
                                                 gxp, hs2, bias, out, flags);
  }
}

// Round 13
// 8668.742 us; speedup vs baseline: 1.6586x; 1.2555x over previous
//
#include <hip/hip_runtime.h>
#include <cstdint>
#include <cstddef>

// Autoregressive LSTM cell with softmax feedback. B=256, T=512, D=512, N=64.
// R13 = R12's x-projection hoist, CHUNKED to fit ws (R12's 1.07GB fp32 gx didn't
// fit -> fallback path ran). T split into 8 chunks of 64 steps:
//   for k: prep_gx_chunk(k) [gx for 64 steps, 134MB]  ->  recur_chunk(k).
// Kernel-boundary release/acquire gives cross-launch visibility of h/c/flags for
// free; in-chunk sync is the R11-verified XCD-local L2 protocol (plain stores +
// volatile loads, no fences, timeout->abort). c-state spills to ws as exact fp32
// between chunks. First step of each chunk needs NO barrier (launch edge is one).
// Everything else verbatim from R11/R12 (verified): frag maps, hi/lo numerics on
// all recurrence operands, split hi/lo LDS planes (conflict-free), XCD self-
// organization via HW_REG_XCC_ID, distributed out-write, gate-per-ct LSTM layout.

typedef _Float16 f16x8 __attribute__((ext_vector_type(8)));
typedef float f32x4 __attribute__((ext_vector_type(4)));
typedef unsigned long long u64;

#define MFMA16(a, b, c_) __builtin_amdgcn_mfma_f32_16x16x32_f16((a), (b), (c_), 0, 0, 0)
#define AGT __HIP_MEMORY_SCOPE_AGENT
#define RLX __ATOMIC_RELAXED

#define HS2_U32 131072   // per h buffer: 256 rows * 512 u32 (f16hi | f16lo<<16)
#define ABORT_OFF 16384  // flags: 256 slots*64 | abort | pad | xcdcnt[8]
#define XCDCNT_OFF 16448
#define FLAG_INTS 16456
#define CHUNK 64

static __device__ __forceinline__ unsigned short f2b(_Float16 h) {
  return __builtin_bit_cast(unsigned short, h);
}
static __device__ __forceinline__ _Float16 b2f(unsigned short s) {
  return __builtin_bit_cast(_Float16, s);
}

__device__ __forceinline__ void cvt8(const float4 a, const float4 b, f16x8& hi, f16x8& lo) {
  float v[8] = {a.x, a.y, a.z, a.w, b.x, b.y, b.z, b.w};
#pragma unroll
  for (int j = 0; j < 8; ++j) {
    _Float16 h = (_Float16)v[j];
    hi[j] = h;
    lo[j] = (_Float16)(v[j] - (float)h);
  }
}

// ---------------------------------------------------------------------------
// prep (identical layouts to R12, all R2-R12 verified).
// ---------------------------------------------------------------------------
__global__ void prep_kernel(const float* __restrict__ x, const float* __restrict__ init_h,
                            const float* __restrict__ W_ih, const float* __restrict__ b_ih,
                            const float* __restrict__ W_hh, const float* __restrict__ b_hh,
                            const float* __restrict__ W_lin, _Float16* __restrict__ wx_hi,
                            _Float16* __restrict__ wx_lo, _Float16* __restrict__ whl_hi,
                            _Float16* __restrict__ whl_lo, _Float16* __restrict__ wlf_hi,
                            unsigned int* __restrict__ hs2, float* __restrict__ bias,
                            int* __restrict__ flags) {
  const int NWF = 128 * 34 * 64;
  const int NWLF = 4 * 16 * 64;
  const int NH2 = 256 * 128;
  long u = (long)blockIdx.x * 256 + threadIdx.x;

  if (u < NWF) {
    int l = (int)(u & 63);
    int u2 = (int)(u >> 6);
    int ki = u2 % 34, sl = u2 / 34;
    int gate = sl & 3, c = sl >> 2;
    int col = gate * 512 + c * 16 + (l & 15);
    int k = ki * 32 + 4 * (l >> 4);
    float4 a, b;
    if (k < 512) {
      const float* p = W_ih + (size_t)col * 576;
      a = *(const float4*)(p + k);
      b = *(const float4*)(p + k + 16);
    } else if (k < 1024) {
      const float* p = W_hh + (size_t)col * 512;
      a = *(const float4*)(p + k - 512);
      b = *(const float4*)(p + k - 512 + 16);
    } else {
      const float* p = W_ih + (size_t)col * 576 + 512;
      a = *(const float4*)(p + k - 1024);
      b = *(const float4*)(p + k - 1024 + 16);
    }
    f16x8 hi, lo;
    cvt8(a, b, hi, lo);
    if (ki < 16) {
      size_t idx = (((size_t)sl * 16 + ki) * 64 + l) * 8;
      *(f16x8*)(wx_hi + idx) = hi;
      *(f16x8*)(wx_lo + idx) = lo;
    } else {
      size_t idx = (((size_t)sl * 18 + (ki - 16)) * 64 + l) * 8;
      *(f16x8*)(whl_hi + idx) = hi;
      *(f16x8*)(whl_lo + idx) = lo;
    }
    return;
  }
  u -= NWF;
  if (u >= 0 && u < NWLF) {
    int l = (int)(u & 63);
    int u2 = (int)(u >> 6);
    int ki = u2 & 15, ct = u2 >> 4;
    int col = ct * 16 + (l & 15);
    int k = ki * 32 + 4 * (l >> 4);
    const float* p = W_lin + (size_t)col * 512;
    float4 a = *(const float4*)(p + k), b = *(const float4*)(p + k + 16);
    f16x8 hi, lo;
    cvt8(a, b, hi, lo);
    *(f16x8*)(wlf_hi + ((size_t)(ct * 16 + ki) * 64 + l) * 8) = hi;
    return;
  }
  u -= NWLF;
  if (u >= 0 && u < NH2) {
    int g4 = (int)(u & 127), row = (int)(u >> 7);
    const float* s = init_h + (size_t)row * 512 + g4 * 4;
    float4 a = *(const float4*)s;
    float v[4] = {a.x, a.y, a.z, a.w};
    unsigned int* d = hs2 + (size_t)row * 512 + g4 * 4;  // buffer 0
#pragma unroll
    for (int j = 0; j < 4; ++j) {
      _Float16 hh = (_Float16)v[j];
      _Float16 hl = (_Float16)(v[j] - (float)hh);
      d[j] = (unsigned int)f2b(hh) | ((unsigned int)f2b(hl) << 16);
    }
    return;
  }
  u -= NH2;
  if (u >= 0 && u < 2048) {
    bias[u] = b_ih[u] + b_hh[u];
    return;
  }
  u -= 2048;
  if (u >= 0 && u < FLAG_INTS) flags[u] = 0;
}

// ---------------------------------------------------------------------------
// prep_gx chunk: gx[tl*256+row][2048] = x[row, t0+tl, :] @ Wx^T (fp32, 3-pass
// hi/lo, R11-verified pieces). Also re-zeroes the flag region for the following
// recur chunk (block (0,0)).
// ---------------------------------------------------------------------------
__global__ void __launch_bounds__(256) prep_gx_kernel(const float* __restrict__ x,
                                                      const _Float16* __restrict__ wx_hi,
                                                      const _Float16* __restrict__ wx_lo,
                                                      float* __restrict__ gx, int t0,
                                                      int* __restrict__ flags) {
  if (blockIdx.x == 0 && blockIdx.y == 0) {
    for (int i = threadIdx.x; i < FLAG_INTS; i += 256) flags[i] = 0;
  }
  const int tl = blockIdx.x >> 4, row16 = blockIdx.x & 15;
  const int w = threadIdx.x >> 6, l = threadIdx.x & 63;
  const int l15 = l & 15, q = l >> 4;
  const int c = blockIdx.y * 4 + w;

  const float* xp = x + (((size_t)(row16 * 16 + l15) * 512 + (t0 + tl)) * 512) + 4 * q;
  const f32x4 Z = {0.f, 0.f, 0.f, 0.f};
  f32x4 acc[4] = {Z, Z, Z, Z};
#pragma unroll 2
  for (int ki = 0; ki < 16; ++ki) {
    float4 av = *(const float4*)(xp + ki * 32);
    float4 bv = *(const float4*)(xp + ki * 32 + 16);
    f16x8 ah, al;
    cvt8(av, bv, ah, al);
#pragma unroll
    for (int gate = 0; gate < 4; ++gate) {
      size_t idx = (((size_t)(c * 4 + gate) * 16 + ki) * 64 + l) * 8;
      f16x8 bh = *(const f16x8*)(wx_hi + idx);
      f16x8 bl = *(const f16x8*)(wx_lo + idx);
      acc[gate] = MFMA16(ah, bh, acc[gate]);
      acc[gate] = MFMA16(al, bh, acc[gate]);
      acc[gate] = MFMA16(ah, bl, acc[gate]);
    }
  }
#pragma unroll
  for (int gate = 0; gate < 4; ++gate)
#pragma unroll
    for (int r = 0; r < 4; ++r)
      gx[((size_t)tl * 256 + row16 * 16 + 4 * q + r) * 2048 + gate * 512 + c * 16 + l15] =
          acc[gate][r];
}

__global__ void __launch_bounds__(512, 1) recur_kernel(
    const float* __restrict__ b_lin, const _Float16* __restrict__ whl_hi_g,
    const _Float16* __restrict__ whl_lo_g, const _Float16* __restrict__ wlf_hi,
    const float* __restrict__ gx, unsigned int* __restrict__ hs2,
    const float* __restrict__ bias, float* __restrict__ cws, float* __restrict__ out,
    int* __restrict__ flags, int s_base, int is_last) {
  const int tid = threadIdx.x;
  const int l = tid & 63, w = tid >> 6;
  const int l15 = l & 15, q = l >> 4;
  const int kh = w & 1, rt = (w >> 1) & 1, ch = w >> 2;  // K-half, row-tile, gate-pair

  __shared__ _Float16 whl_h[36864];  // 72KB h|y-part gate B-frag hi
  __shared__ _Float16 whl_l[36864];  // 72KB lo plane (separate -> conflict-free)
  __shared__ float scratch[2304];    // 9KB union: y-merge | ytr | gate-merge
  __shared__ int s_ab, s_g, s_c;

  // ---- self-organize into the block's PHYSICAL XCD (R11-verified) ----
  if (tid == 0) {
    s_ab = 0;
    int xcc = __builtin_amdgcn_s_getreg(63508) & 7;  // HW_REG_XCC_ID
    int slot = __hip_atomic_fetch_add(flags + XCDCNT_OFF + xcc, 1, RLX, AGT);
    s_g = xcc;
    s_c = slot;
    if (slot >= 32) {
      __hip_atomic_store(flags + ABORT_OFF, 1, RLX, AGT);
      s_ab = 1;
    }
  }
  __syncthreads();
  if (s_ab) return;  // peers time out -> visible failure (no hang)
  const int g = s_g, c = s_c;
  const int ct0 = ch * 2, ct1 = ch * 2 + 1;

  {  // stage this block's h|y-part gate weights: 4608 float4 units per plane
    const _Float16* sh = whl_hi_g + (size_t)c * 36864;
    const _Float16* slo = whl_lo_g + (size_t)c * 36864;
#pragma unroll
    for (int i = 0; i < 9; ++i) {
      int uu = tid + i * 512;
      *(float4*)(whl_h + (size_t)uu * 8) = *(const float4*)(sh + (size_t)uu * 8);
      *(float4*)(whl_l + (size_t)uu * 8) = *(const float4*)(slo + (size_t)uu * 8);
    }
  }
  __syncthreads();

  float bg[4];
#pragma unroll
  for (int gi = 0; gi < 4; ++gi) bg[gi] = bias[gi * 512 + c * 16 + l15];
  const float blv0 = b_lin[l15], blv1 = b_lin[16 + l15];
  const float blv2 = b_lin[32 + l15], blv3 = b_lin[48 + l15];

  const int rowA = g * 32 + rt * 16 + l15;  // A-frag source row (global)
  const unsigned int* hldA = hs2 + (size_t)rowA * 512 + 4 * q;

  int* abortf = flags + ABORT_OFF;

  auto ARRIVE = [&](int v) {
    __syncthreads();  // drains this block's h stores (vmcnt) before the flag
    if (tid == 0) *(volatile int*)(flags + (size_t)(g * 32 + c) * 64) = v;
  };
  auto WAIT = [&](int v) -> bool {
    if (tid < 32) {
      int a = 0;
      volatile int* f = (volatile int*)(flags + ((size_t)g * 32 + tid) * 64);
      int it = 0;
      while (*f < v) {
        __builtin_amdgcn_s_sleep(1);
        if (++it > 300000) {
          a = 1;
          break;
        }
        if ((it & 255) == 0 && __hip_atomic_load(abortf, RLX, AGT) != 0) {
          a = 1;
          break;
        }
      }
      a = __any(a) ? 1 : 0;
      if (tid == 0) {
        if (a) __hip_atomic_store(abortf, 1, RLX, AGT);
        s_ab = a;
      }
    }
    __syncthreads();
    return s_ab != 0;
  };

  // h|y k-chunk, 3-pass hi/lo, B from split LDS planes (kidx 0..15 h, 16..17 y)
  auto GKH = [&](const f16x8& ah, const f16x8& al, int kidx, f32x4& A0, f32x4& A1) {
    const _Float16* p0h = whl_h + (((size_t)ct0 * 18 + kidx) * 64 + l) * 8;
    const _Float16* p1h = whl_h + (((size_t)ct1 * 18 + kidx) * 64 + l) * 8;
    const _Float16* p0l = whl_l + (((size_t)ct0 * 18 + kidx) * 64 + l) * 8;
    const _Float16* p1l = whl_l + (((size_t)ct1 * 18 + kidx) * 64 + l) * 8;
    f16x8 b0h = *(const f16x8*)p0h, b1h = *(const f16x8*)p1h;
    f16x8 b0l = *(const f16x8*)p0l, b1l = *(const f16x8*)p1l;
    A0 = MFMA16(ah, b0h, A0);
    A1 = MFMA16(ah, b1h, A1);
    A0 = MFMA16(al, b0h, A0);
    A1 = MFMA16(al, b1h, A1);
    A0 = MFMA16(ah, b0l, A0);
    A1 = MFMA16(ah, b1l, A1);
  };

  const f32x4 Z = {0.f, 0.f, 0.f, 0.f};
  const int rowE0 = g * 32 + rt * 16 + 4 * q;  // LSTM rows rowE0+r, d = 16c+l15
  const int dglob = c * 16 + l15;
  float cst[4];
  if (kh == 0 && ch == 0) {
#pragma unroll
    for (int r = 0; r < 4; ++r)
      cst[r] = (s_base == 0) ? 0.f : cws[(size_t)(rowE0 + r) * 512 + dglob];
  }

#pragma unroll 1
  for (int sl = 0; sl < CHUNK; ++sl) {
    const int s = s_base + sl;

    // ---- gx prefetch (owning lanes; independent of the barrier) ----
    float gxv[4][4];
    if (kh == 0 && ch == 0) {
#pragma unroll
      for (int r = 0; r < 4; ++r) {
        const float* gp = gx + ((size_t)sl * 256 + rowE0 + r) * 2048 + dglob;
#pragma unroll
        for (int gate = 0; gate < 4; ++gate) gxv[gate][r] = gp[gate * 512];
      }
    }

    if (sl > 0) {  // first step of a chunk: launch boundary already synced h
      if (WAIT(sl)) return;
    }

    // ---- h frag loads: volatile u64 (L1-bypass; local-L2 dirty lines) ----
    f16x8 hh[8], hl[8];
    const unsigned int* hp0 = hldA + (size_t)(s & 1) * HS2_U32;
#pragma unroll
    for (int i = 0; i < 8; ++i) {
      const unsigned int* hp = hp0 + (kh * 8 + i) * 32;
      u64 u0 = *(const volatile u64*)hp;
      u64 u1 = *(const volatile u64*)(hp + 2);
      u64 u2 = *(const volatile u64*)(hp + 16);
      u64 u3 = *(const volatile u64*)(hp + 18);
      unsigned int wd[8] = {(unsigned int)u0, (unsigned int)(u0 >> 32),
                            (unsigned int)u1, (unsigned int)(u1 >> 32),
                            (unsigned int)u2, (unsigned int)(u2 >> 32),
                            (unsigned int)u3, (unsigned int)(u3 >> 32)};
#pragma unroll
      for (int j = 0; j < 8; ++j) {
        hh[i][j] = b2f((unsigned short)(wd[j] & 0xffffu));
        hl[i][j] = b2f((unsigned short)(wd[j] >> 16));
      }
    }

    // ---- y-GEMM partials (ch==0 waves; B = W_lin-hi from L2, 2-pass) ----
    f32x4 y0 = Z, y1 = Z, y2 = Z, y3 = Z;
    if (s > 0 && ch == 0) {
#pragma unroll
      for (int i = 0; i < 8; ++i) {
        int ki = kh * 8 + i;
        f16x8 b0 = *(const f16x8*)(wlf_hi + (((size_t)(0 * 16 + ki)) * 64 + l) * 8);
        f16x8 b1 = *(const f16x8*)(wlf_hi + (((size_t)(1 * 16 + ki)) * 64 + l) * 8);
        f16x8 b2 = *(const f16x8*)(wlf_hi + (((size_t)(2 * 16 + ki)) * 64 + l) * 8);
        f16x8 b3 = *(const f16x8*)(wlf_hi + (((size_t)(3 * 16 + ki)) * 64 + l) * 8);
        y0 = MFMA16(hh[i], b0, y0);
        y1 = MFMA16(hh[i], b1, y1);
        y2 = MFMA16(hh[i], b2, y2);
        y3 = MFMA16(hh[i], b3, y3);
        y0 = MFMA16(hl[i], b0, y0);
        y1 = MFMA16(hl[i], b1, y1);
        y2 = MFMA16(hl[i], b2, y2);
        y3 = MFMA16(hl[i], b3, y3);
      }
    }
    // ---- h-GEMM (B from LDS) ----
    f32x4 aC0 = Z, aC1 = Z;
#pragma unroll
    for (int i = 0; i < 8; ++i) GKH(hh[i], hl[i], kh * 8 + i, aC0, aC1);

    if (s > 0) {
      if (ch == 0 && kh == 1) {  // y K-half dump
#pragma unroll
        for (int r = 0; r < 4; ++r) {
          scratch[((rt * 4 + 0) * 4 + r) * 64 + l] = y0[r];
          scratch[((rt * 4 + 1) * 4 + r) * 64 + l] = y1[r];
          scratch[((rt * 4 + 2) * 4 + r) * 64 + l] = y2[r];
          scratch[((rt * 4 + 3) * 4 + r) * 64 + l] = y3[r];
        }
      }
      __syncthreads();  // S1
      if (ch == 0 && kh == 0) {
        float la[4][4];
#pragma unroll
        for (int r = 0; r < 4; ++r) {
          la[0][r] = y0[r] + scratch[((rt * 4 + 0) * 4 + r) * 64 + l] + blv0;
          la[1][r] = y1[r] + scratch[((rt * 4 + 1) * 4 + r) * 64 + l] + blv1;
          la[2][r] = y2[r] + scratch[((rt * 4 + 2) * 4 + r) * 64 + l] + blv2;
          la[3][r] = y3[r] + scratch[((rt * 4 + 3) * 4 + r) * 64 + l] + blv3;
        }
#pragma unroll
        for (int r = 0; r < 4; ++r) {  // softmax over 64 cols (16 lanes x 4 ct)
          float mx = fmaxf(fmaxf(la[0][r], la[1][r]), fmaxf(la[2][r], la[3][r]));
          mx = fmaxf(mx, __shfl_xor(mx, 1));
          mx = fmaxf(mx, __shfl_xor(mx, 2));
          mx = fmaxf(mx, __shfl_xor(mx, 4));
          mx = fmaxf(mx, __shfl_xor(mx, 8));
          float e0 = __expf(la[0][r] - mx), e1 = __expf(la[1][r] - mx);
          float e2 = __expf(la[2][r] - mx), e3 = __expf(la[3][r] - mx);
          float sm = e0 + e1 + e2 + e3;
          sm += __shfl_xor(sm, 1);
          sm += __shfl_xor(sm, 2);
          sm += __shfl_xor(sm, 4);
          sm += __shfl_xor(sm, 8);
          float inv = 1.f / sm;
          la[0][r] = e0 * inv;
          la[1][r] = e1 * inv;
          la[2][r] = e2 * inv;
          la[3][r] = e3 * inv;
        }
        // distributed out-write: this block owns y-cols 2c, 2c+1
#pragma unroll
        for (int j2 = 0; j2 < 2; ++j2) {
          int n = 2 * c + j2;
          if (l15 == (n & 15)) {
#pragma unroll
            for (int r = 0; r < 4; ++r)
              out[((size_t)(g * 32 + rt * 16 + 4 * q + r) * 512 + (s - 1)) * 64 + n] =
                  la[n >> 4][r];
          }
        }
        // ytr (hi|lo planes) for the y-feedback A-frags
        _Float16* yt = (_Float16*)scratch;
#pragma unroll
        for (int r = 0; r < 4; ++r) {
          int row = rt * 16 + 4 * q + r;
#pragma unroll
          for (int ct = 0; ct < 4; ++ct) {
            _Float16 vh = (_Float16)la[ct][r];
            _Float16 vl = (_Float16)(la[ct][r] - (float)vh);
            yt[row * 136 + ct * 16 + l15] = vh;
            yt[row * 136 + 72 + ct * 16 + l15] = vl;
          }
        }
      }
      __syncthreads();  // S2: ytr ready
      {
        const _Float16* yt = (const _Float16*)scratch + (rt * 16 + l15) * 136 + kh * 32 + 4 * q;
        union {
          u64 d[2];
          f16x8 v;
        } th, tl;
        th.d[0] = *(const u64*)yt;
        th.d[1] = *(const u64*)(yt + 16);
        tl.d[0] = *(const u64*)(yt + 72);
        tl.d[1] = *(const u64*)(yt + 88);
        GKH(th.v, tl.v, 16 + kh, aC0, aC1);  // y-feedback k-chunk (hi/lo, LDS B)
      }
      __syncthreads();  // S3: ytr reads done; scratch free for gate merge
    }

    // ---- 4-way gate merge (kh x ch) ----
    if (kh == 1) {
#pragma unroll
      for (int r = 0; r < 4; ++r) {
        scratch[((rt * 4 + ct0) * 4 + r) * 64 + l] = aC0[r];
        scratch[((rt * 4 + ct1) * 4 + r) * 64 + l] = aC1[r];
      }
    }
    __syncthreads();  // S4
    if (kh == 0) {
#pragma unroll
      for (int r = 0; r < 4; ++r) {
        aC0[r] += scratch[((rt * 4 + ct0) * 4 + r) * 64 + l];
        aC1[r] += scratch[((rt * 4 + ct1) * 4 + r) * 64 + l];
      }
      if (ch == 1) {  // publish summed g,o for the LSTM waves
#pragma unroll
        for (int r = 0; r < 4; ++r) {
          scratch[((rt * 4 + 2) * 4 + r) * 64 + l] = aC0[r];
          scratch[((rt * 4 + 3) * 4 + r) * 64 + l] = aC1[r];
        }
      }
    }
    __syncthreads();  // S5
    if (kh == 0 && ch == 0) {
      // ---- elementwise LSTM (gx added at bias stage, exact fp32) ----
      const unsigned int wbuf = (unsigned int)(((s + 1) & 1) * HS2_U32);
#pragma unroll
      for (int r = 0; r < 4; ++r) {
        float zi = aC0[r] + bg[0] + gxv[0][r];
        float zf = aC1[r] + bg[1] + gxv[1][r];
        float zg = scratch[((rt * 4 + 2) * 4 + r) * 64 + l] + bg[2] + gxv[2][r];
        float zo = scratch[((rt * 4 + 3) * 4 + r) * 64 + l] + bg[3] + gxv[3][r];
        float iv = 1.f / (1.f + __expf(-zi));
        float fv = 1.f / (1.f + __expf(-zf));
        float eg = __expf(2.f * zg);
        float gv = 1.f - 2.f / (eg + 1.f);
        float ov = 1.f / (1.f + __expf(-zo));
        float cn = fv * cst[r] + iv * gv;
        cst[r] = cn;
        float ec = __expf(2.f * cn);
        float th2 = 1.f - 2.f / (ec + 1.f);
        float hv = ov * th2;
        _Float16 hhv = (_Float16)hv;
        _Float16 hlv = (_Float16)(hv - (float)hhv);
        unsigned int pk = (unsigned int)f2b(hhv) | ((unsigned int)f2b(hlv) << 16);
        hs2[wbuf + (size_t)(rowE0 + r) * 512 + dglob] = pk;  // PLAIN store -> local L2
      }
    }
    ARRIVE(sl + 1);  // drain + publish h_s (group-local flag via L2)
  }

  // ---- spill c-state for the next chunk (exact fp32) ----
  if (kh == 0 && ch == 0) {
#pragma unroll
    for (int r = 0; r < 4; ++r) cws[(size_t)(rowE0 + r) * 512 + dglob] = cst[r];
  }
  if (!is_last) return;

  // ---- epilogue (last chunk): y_511 from h_511 (buffer 0) ----
  if (WAIT(CHUNK)) return;
  {
    f16x8 hh[8], hl[8];
#pragma unroll
    for (int i = 0; i < 8; ++i) {
      const unsigned int* hp = hldA + (kh * 8 + i) * 32;  // buffer (512&1)==0
      u64 u0 = *(const volatile u64*)hp;
      u64 u1 = *(const volatile u64*)(hp + 2);
      u64 u2 = *(const volatile u64*)(hp + 16);
      u64 u3 = *(const volatile u64*)(hp + 18);
      unsigned int wd[8] = {(unsigned int)u0, (unsigned int)(u0 >> 32),
                            (unsigned int)u1, (unsigned int)(u1 >> 32),
                            (unsigned int)u2, (unsigned int)(u2 >> 32),
                            (unsigned int)u3, (unsigned int)(u3 >> 32)};
#pragma unroll
      for (int j = 0; j < 8; ++j) {
        hh[i][j] = b2f((unsigned short)(wd[j] & 0xffffu));
        hl[i][j] = b2f((unsigned short)(wd[j] >> 16));
      }
    }
    f32x4 y0 = Z, y1 = Z, y2 = Z, y3 = Z;
    if (ch == 0) {
#pragma unroll
      for (int i = 0; i < 8; ++i) {
        int ki = kh * 8 + i;
        f16x8 b0 = *(const f16x8*)(wlf_hi + (((size_t)(0 * 16 + ki)) * 64 + l) * 8);
        f16x8 b1 = *(const f16x8*)(wlf_hi + (((size_t)(1 * 16 + ki)) * 64 + l) * 8);
        f16x8 b2 = *(const f16x8*)(wlf_hi + (((size_t)(2 * 16 + ki)) * 64 + l) * 8);
        f16x8 b3 = *(const f16x8*)(wlf_hi + (((size_t)(3 * 16 + ki)) * 64 + l) * 8);
        y0 = MFMA16(hh[i], b0, y0);
        y1 = MFMA16(hh[i], b1, y1);
        y2 = MFMA16(hh[i], b2, y2);
        y3 = MFMA16(hh[i], b3, y3);
        y0 = MFMA16(hl[i], b0, y0);
        y1 = MFMA16(hl[i], b1, y1);
        y2 = MFMA16(hl[i], b2, y2);
        y3 = MFMA16(hl[i], b3, y3);
      }
      if (kh == 1) {
#pragma unroll
        for (int r = 0; r < 4; ++r) {
          scratch[((rt * 4 + 0) * 4 + r) * 64 + l] = y0[r];
          scratch[((rt * 4 + 1) * 4 + r) * 64 + l] = y1[r];
          scratch[((rt * 4 + 2) * 4 + r) * 64 + l] = y2[r];
          scratch[((rt * 4 + 3) * 4 + r) * 64 + l] = y3[r];
        }
      }
    }
    __syncthreads();
    if (ch == 0 && kh == 0) {
      float la[4][4];
#pragma unroll
      for (int r = 0; r < 4; ++r) {
        la[0][r] = y0[r] + scratch[((rt * 4 + 0) * 4 + r) * 64 + l] + blv0;
        la[1][r] = y1[r] + scratch[((rt * 4 + 1) * 4 + r) * 64 + l] + blv1;
        la[2][r] = y2[r] + scratch[((rt * 4 + 2) * 4 + r) * 64 + l] + blv2;
        la[3][r] = y3[r] + scratch[((rt * 4 + 3) * 4 + r) * 64 + l] + blv3;
      }
#pragma unroll
      for (int r = 0; r < 4; ++r) {
        float mx = fmaxf(fmaxf(la[0][r], la[1][r]), fmaxf(la[2][r], la[3][r]));
        mx = fmaxf(mx, __shfl_xor(mx, 1));
        mx = fmaxf(mx, __shfl_xor(mx, 2));
        mx = fmaxf(mx, __shfl_xor(mx, 4));
        mx = fmaxf(mx, __shfl_xor(mx, 8));
        float e0 = __expf(la[0][r] - mx), e1 = __expf(la[1][r] - mx);
        float e2 = __expf(la[2][r] - mx), e3 = __expf(la[3][r] - mx);
        float sm = e0 + e1 + e2 + e3;
        sm += __shfl_xor(sm, 1);
        sm += __shfl_xor(sm, 2);
        sm += __shfl_xor(sm, 4);
        sm += __shfl_xor(sm, 8);
        float inv = 1.f / sm;
        la[0][r] = e0 * inv;
        la[1][r] = e1 * inv;
        la[2][r] = e2 * inv;
        la[3][r] = e3 * inv;
      }
#pragma unroll
      for (int j2 = 0; j2 < 2; ++j2) {
        int n = 2 * c + j2;
        if (l15 == (n & 15)) {
#pragma unroll
          for (int r = 0; r < 4; ++r)
            out[((size_t)(g * 32 + rt * 16 + 4 * q + r) * 512 + 511) * 64 + n] = la[n >> 4][r];
        }
      }
    }
  }
}

extern "C" void kernel_launch(void* const* d_in, const int* in_sizes, int n_in, void* d_out,
                              int out_size, void* d_ws, size_t ws_size, hipStream_t stream) {
  const float* x = (const float*)d_in[0];
  const float* init_h = (const float*)d_in[1];
  const float* W_ih = (const float*)d_in[2];
  const float* b_ih = (const float*)d_in[3];
  const float* W_hh = (const float*)d_in[4];
  const float* b_hh = (const float*)d_in[5];
  const float* W_lin = (const float*)d_in[6];
  const float* b_lin = (const float*)d_in[7];
  float* out = (float*)d_out;
  (void)in_sizes;
  (void)n_in;
  (void)out_size;

  char* ws = (char*)d_ws;
  size_t off = 0;
  auto take = [&](size_t bytes) -> char* {
    char* r = ws + off;
    off = (off + bytes + 255) & ~(size_t)255;
    return r;
  };
  const size_t WX_E = (size_t)128 * 16 * 64 * 8;   // x-part gate frags, per plane
  const size_t WHL_E = (size_t)128 * 18 * 64 * 8;  // h|y-part gate frags, per plane
  const size_t WLF_E = (size_t)4 * 16 * 64 * 8;    // W_lin hi frags
  const size_t GX_E = (size_t)CHUNK * 256 * 2048;  // per-chunk x-gates (fp32)

  _Float16* wx_hi = (_Float16*)take(WX_E * 2);
  _Float16* wx_lo = (_Float16*)take(WX_E * 2);
  _Float16* whl_hi = (_Float16*)take(WHL_E * 2);
  _Float16* whl_lo = (_Float16*)take(WHL_E * 2);
  _Float16* wlf_hi = (_Float16*)take(WLF_E * 2);
  unsigned int* hs2 = (unsigned int*)take((size_t)2 * HS2_U32 * 4);
  float* bias = (float*)take(2048 * 4);
  int* flags = (int*)take((size_t)FLAG_INTS * 4);
  float* cws = (float*)take((size_t)256 * 512 * 4);
  float* gxp = (float*)take(GX_E * 4);  // 134 MB
  if (ws_size < off) return;            // cannot run -> visible failure

  const long total = 278528L + 4096 + 32768 + 2048 + FLAG_INTS;
  prep_kernel<<<(int)((total + 255) / 256), 256, 0, stream>>>(
      x, init_h, W_ih, b_ih, W_hh, b_hh, W_lin, wx_hi, wx_lo, whl_hi, whl_lo, wlf_hi, hs2, bias,
      flags);
  for (int k = 0; k < 512 / CHUNK; ++k) {
    prep_gx_kernel<<<dim3(16 * CHUNK, 8), 256, 0, stream>>>(x, wx_hi, wx_lo, gxp, k * CHUNK,
                                                            flags);
    recur_kernel<<<256, 512, 0, stream>>>(b_lin, whl_hi, whl_lo, wlf_hi, gxp, hs2, bias, cws,
                                          out, flags, k * CHUNK, k == (512 / CHUNK - 1));
  }
}